// Round 21
// baseline (142.068 us; speedup 1.0000x reference)
//
#include <hip/hip_runtime.h>
#include <stdint.h>

#define NHITS 100000
#define NOBJ  1024
#define HALF  50000
#define QUART 25000
#define HALF_PAIRS 51200000u   // NHITS*NOBJ/2
#define QCAP 2048              // per-wave queue entries (16 KB total LDS)

// ---------------- ws layout (bytes) ----------------
// 0:   double v_att_sum
// 8:   double v_rep_sum
// 16:  double coward_sum
// 24:  double noise_sum
// 32:  ull    noise_cnt
// 40:  u32    nrep
// 48:  float  freq (unused)
// 64:   ull   packed[1024]                        (64..8256)   (memset-0 init)
// 8256: float arec[1024*16] {x[12], qa, xxa,0,0}  (8256..73792)
// 73792:  float q_arr[100000]                     (73792..473792)
// 473792: float xx_arr[100000]                    (473792..873792)
// 873792: u64 maskbuf[16][100000] = 12.8MB        (873792..13673792)

#define MASK_OFF 873792ull
#define WS_NEED (MASK_OFF + 16ull * NHITS * 8ull)

__device__ inline uint32_t rotl32(uint32_t x, int n) {
    return (x << n) | (x >> (32 - n));
}

__device__ inline void threefry2x32(uint32_t k0, uint32_t k1,
                                    uint32_t x0, uint32_t x1,
                                    uint32_t& o0, uint32_t& o1) {
    uint32_t ks2 = k0 ^ k1 ^ 0x1BD11BDAu;
    x0 += k0; x1 += k1;
#define TF_ROUND(r) { x0 += x1; x1 = rotl32(x1, r); x1 ^= x0; }
    TF_ROUND(13) TF_ROUND(15) TF_ROUND(26) TF_ROUND(6)
    x0 += k1;  x1 += ks2 + 1u;
    TF_ROUND(17) TF_ROUND(29) TF_ROUND(16) TF_ROUND(24)
    x0 += ks2; x1 += k0 + 2u;
    TF_ROUND(13) TF_ROUND(15) TF_ROUND(26) TF_ROUND(6)
    x0 += k0;  x1 += k1 + 3u;
    TF_ROUND(17) TF_ROUND(29) TF_ROUND(16) TF_ROUND(24)
    x0 += k1;  x1 += ks2 + 4u;
    TF_ROUND(13) TF_ROUND(15) TF_ROUND(26) TF_ROUND(6)
    x0 += ks2; x1 += k0 + 5u;
#undef TF_ROUND
    o0 = x0; o1 = x1;
}

__device__ inline float tf_uniform(uint32_t bits) {
    return __uint_as_float((bits >> 9) | 0x3f800000u) - 1.0f;
}

__device__ inline float freq_from_n(unsigned int n) {
    if (n < 1u) n = 1u;
    return fminf(100000.0f / (float)n, 1.0f);
}

__device__ inline double waveReduceD(double v) {
    for (int off = 32; off > 0; off >>= 1) v += __shfl_down(v, off, 64);
    return v;
}
__device__ inline unsigned int waveReduceU(unsigned int v) {
    for (int off = 32; off > 0; off >>= 1) v += __shfl_down(v, off, 64);
    return v;
}

#define DOT12(XA, XB, XC, A, B, C) \
    fmaf((XC).w, (C).w, fmaf((XC).z, (C).z, fmaf((XC).y, (C).y, fmaf((XC).x, (C).x, \
    fmaf((XB).w, (B).w, fmaf((XB).z, (B).z, fmaf((XB).y, (B).y, fmaf((XB).x, (B).x, \
    fmaf((XA).w, (A).w, fmaf((XA).z, (A).z, fmaf((XA).y, (A).y, (XA).x * (A).x)))))))))))

#define SS12(XA, XB, XC) DOT12(XA, XB, XC, XA, XB, XC)

// ---------------- kernels ----------------

__global__ void k_hits(const float* __restrict__ beta,
                       const float* __restrict__ x,
                       const int* __restrict__ oid,
                       unsigned long long* __restrict__ packed,
                       float* __restrict__ q_arr,
                       float* __restrict__ xx_arr,
                       double* __restrict__ noise_sum,
                       unsigned long long* __restrict__ noise_cnt) {
    int j = blockIdx.x * blockDim.x + threadIdx.x;
    float nb = 0.0f;
    unsigned int nc = 0;
    if (j < NHITS) {
        float b = beta[j];
        int o = oid[j];
        float a = atanhf(b);
        float q = a * a + 0.1f;
        q_arr[j] = q;
        const float4* x4 = (const float4*)x;
        float4 A = x4[j * 3 + 0], B = x4[j * 3 + 1], C = x4[j * 3 + 2];
        xx_arr[j] = SS12(A, B, C);
        if (o > 0) {
            // packed init is 0 (memset); any hit's value exceeds 0 since q>0.1
            unsigned long long p =
                ((unsigned long long)__float_as_uint(q) << 32) |
                (unsigned long long)(0xFFFFFFFFu - (unsigned)j);
            atomicMax(&packed[o - 1], p);
        } else {
            nb = b; nc = 1;
        }
    }
    double rb = waveReduceD((double)nb);
    unsigned int rc = waveReduceU(nc);
    if ((threadIdx.x & 63) == 0) {
        if (rb != 0.0) atomicAdd(noise_sum, rb);
        if (rc)        atomicAdd(noise_cnt, (unsigned long long)rc);
    }
}

__global__ void k_alphas(const unsigned long long* __restrict__ packed,
                         const float* __restrict__ x,
                         const float* __restrict__ beta,
                         const float* __restrict__ q_arr,
                         const float* __restrict__ xx_arr,
                         float* __restrict__ arec,
                         double* __restrict__ coward_sum) {
    int k = blockIdx.x * blockDim.x + threadIdx.x;
    double c = 0.0;
    if (k < NOBJ) {
        unsigned idx = 0xFFFFFFFFu - (unsigned)(packed[k] & 0xFFFFFFFFull);
        if (idx >= NHITS) idx = 0;   // hitless object: reference argmax gives 0
        const float4* x4 = (const float4*)x;
        float4 A = x4[idx * 3 + 0];
        float4 B = x4[idx * 3 + 1];
        float4 C = x4[idx * 3 + 2];
        float4 D;
        D.x = q_arr[idx]; D.y = xx_arr[idx]; D.z = 0.f; D.w = 0.f;
        float4* ar = (float4*)arec;
        ar[k * 4 + 0] = A;
        ar[k * 4 + 1] = B;
        ar[k * 4 + 2] = C;
        ar[k * 4 + 3] = D;
        c = 1.0 - (double)beta[idx];
    }
    double rc = waveReduceD(c);
    if ((threadIdx.x & 63) == 0) atomicAdd(coward_sum, rc);
}

// scan: round-12 codegen (named float4 hits + LDS object tile + scalar DOT12)
// with v_att computed IN the mask loop, reusing t0..t3 when kl == rel.
// No post-loop hit liveness -> register peak stays near the 52-reg form.
__global__ __launch_bounds__(256)
void k_scan(const float* __restrict__ x,
            const float* __restrict__ q_arr,
            const float* __restrict__ xx_arr,
            const int* __restrict__ oid,
            const float* __restrict__ arec,
            unsigned long long* __restrict__ mb64,
            unsigned int* __restrict__ nrep,
            double* __restrict__ v_att_sum,
            int do_write) {
    __shared__ float4 spack[64 * 4];    // 4 KB: 64 objects x {A,B,C,D}
    __shared__ unsigned int su[4];
    __shared__ double sd[4];
    const int tid = threadIdx.x;
    const int kb = blockIdx.y * 64;
    const float4* ar4 = (const float4*)arec;
    spack[tid] = ar4[kb * 4 + tid];
    __syncthreads();

    const int t = blockIdx.x * 256 + tid;
    const bool valid = t < QUART;
    const int j0 = valid ? t : 0;
    const int j1 = j0 + QUART;
    const int j2 = j0 + 2 * QUART;
    const int j3 = j0 + 3 * QUART;
    const float4* x4 = (const float4*)x;

    float4 X0a = x4[j0 * 3 + 0], X0b = x4[j0 * 3 + 1], X0c = x4[j0 * 3 + 2];
    float4 X1a = x4[j1 * 3 + 0], X1b = x4[j1 * 3 + 1], X1c = x4[j1 * 3 + 2];
    float4 X2a = x4[j2 * 3 + 0], X2b = x4[j2 * 3 + 1], X2c = x4[j2 * 3 + 2];
    float4 X3a = x4[j3 * 3 + 0], X3b = x4[j3 * 3 + 1], X3c = x4[j3 * 3 + 2];

    const float inval = valid ? 0.0f : 3e9f;
    const float xx0 = xx_arr[j0] + inval;
    const float xx1 = xx_arr[j1] + inval;
    const float xx2 = xx_arr[j2] + inval;
    const float xx3 = xx_arr[j3] + inval;
    const int o0 = valid ? oid[j0] : 0;
    const int o1 = valid ? oid[j1] : 0;
    const int o2 = valid ? oid[j2] : 0;
    const int o3 = valid ? oid[j3] : 0;
    const int relA = (o0 > 0) ? (o0 - 1 - kb) : -1;
    const int relB = (o1 > 0) ? (o1 - 1 - kb) : -1;
    const int relC = (o2 > 0) ? (o2 - 1 - kb) : -1;
    const int relD = (o3 > 0) ? (o3 - 1 - kb) : -1;
    const float q0 = q_arr[j0];
    const float q1 = q_arr[j1];
    const float q2 = q_arr[j2];
    const float q3 = q_arr[j3];

    uint32_t mA0 = 0, mA1 = 0, mB0 = 0, mB1 = 0;
    uint32_t mC0 = 0, mC1 = 0, mD0 = 0, mD1 = 0;
    double vatt = 0.0;

#define SCANH(BASE, MA, MB, MC, MD)                                         \
    {                                                                       \
        uint32_t bit = 1u;                                                  \
        for (int kk = 0; kk < 32; ++kk, bit += bit) {                       \
            int kl = (BASE) + kk;                                           \
            float4 A = spack[kl * 4 + 0];                                   \
            float4 B = spack[kl * 4 + 1];                                   \
            float4 C = spack[kl * 4 + 2];                                   \
            float a2 = spack[kl * 4 + 3].y;                                 \
            float d0 = DOT12(X0a, X0b, X0c, A, B, C);                       \
            float d1 = DOT12(X1a, X1b, X1c, A, B, C);                       \
            float d2 = DOT12(X2a, X2b, X2c, A, B, C);                       \
            float d3 = DOT12(X3a, X3b, X3c, A, B, C);                       \
            float t0 = fmaf(-2.0f, d0, xx0) + a2;                           \
            float t1 = fmaf(-2.0f, d1, xx1) + a2;                           \
            float t2 = fmaf(-2.0f, d2, xx2) + a2;                           \
            float t3 = fmaf(-2.0f, d3, xx3) + a2;                           \
            const bool aA = (kl == relA);                                   \
            const bool aB = (kl == relB);                                   \
            const bool aC = (kl == relC);                                   \
            const bool aD = (kl == relD);                                   \
            MA |= (t0 < 1.0f && !aA) ? bit : 0u;                            \
            MB |= (t1 < 1.0f && !aB) ? bit : 0u;                            \
            MC |= (t2 < 1.0f && !aC) ? bit : 0u;                            \
            MD |= (t3 < 1.0f && !aD) ? bit : 0u;                            \
            if (aA | aB | aC | aD) {                                        \
                float qa_o = spack[kl * 4 + 3].x;                           \
                if (aA) vatt += (double)((q0 * qa_o) * fmaxf(t0, 0.0f));    \
                if (aB) vatt += (double)((q1 * qa_o) * fmaxf(t1, 0.0f));    \
                if (aC) vatt += (double)((q2 * qa_o) * fmaxf(t2, 0.0f));    \
                if (aD) vatt += (double)((q3 * qa_o) * fmaxf(t3, 0.0f));    \
            }                                                               \
        }                                                                   \
    }
    SCANH(0,  mA0, mB0, mC0, mD0)
    SCANH(32, mA1, mB1, mC1, mD1)
#undef SCANH

    const unsigned long long M0 = (unsigned long long)mA0 | ((unsigned long long)mA1 << 32);
    const unsigned long long M1 = (unsigned long long)mB0 | ((unsigned long long)mB1 << 32);
    const unsigned long long M2 = (unsigned long long)mC0 | ((unsigned long long)mC1 << 32);
    const unsigned long long M3 = (unsigned long long)mD0 | ((unsigned long long)mD1 << 32);

    if (do_write && valid) {
        const size_t W = (size_t)blockIdx.y;
        mb64[W * NHITS + j0] = M0;
        mb64[W * NHITS + j1] = M1;
        mb64[W * NHITS + j2] = M2;
        mb64[W * NHITS + j3] = M3;
    }

    unsigned int cnt = (unsigned)(__popcll(M0) + __popcll(M1) +
                                  __popcll(M2) + __popcll(M3));
    unsigned int rc = waveReduceU(cnt);
    double rv = waveReduceD(vatt);
    if ((tid & 63) == 0) { su[tid >> 6] = rc; sd[tid >> 6] = rv; }
    __syncthreads();
    if (tid == 0) {
        unsigned int s = su[0] + su[1] + su[2] + su[3];
        if (s) atomicAdd(nrep, s);
        double v = sd[0] + sd[1] + sd[2] + sd[3];
        if (v != 0.0) atomicAdd(v_att_sum, v);
    }
}

// rep: u64 mask words, 4 rounds/block, per-wave LDS queue balancing.
// grid (98, 16): blockIdx.y = u64 word index W (objects [W*64, W*64+64)).
// QCAP=2048 entries/wave (16 KB LDS) with dormant overflow guard.
__global__ __launch_bounds__(256)
void k_rep(const float* __restrict__ x,
           const float* __restrict__ q_arr,
           const float* __restrict__ xx_arr,
           const float* __restrict__ arec,
           const unsigned long long* __restrict__ mb64,
           const unsigned int* __restrict__ nrep,
           double* __restrict__ acc_out) {
    __shared__ unsigned short qq[4][QCAP];   // 16 KB
    __shared__ double sd[4];
    const int tid = threadIdx.x;
    const int lane = tid & 63;
    const int w = tid >> 6;
    const int W = blockIdx.y;
    const int jblk = blockIdx.x * 1024;
    const float freq = freq_from_n(*nrep);
    const float4* x4 = (const float4*)x;
    const float4* ar = (const float4*)arec;
    double acc = 0.0;

#define REP_PAIR(JJ, KK)                                                        \
    {                                                                           \
        int jj = (JJ); int k = (KK);                                            \
        uint32_t f = (uint32_t)jj * NOBJ + (uint32_t)k;                         \
        bool lo = jj < HALF;                                                    \
        uint32_t xa = lo ? f : (f - HALF_PAIRS);                                \
        uint32_t r0, r1;                                                        \
        threefry2x32(0u, 42u, xa, xa + HALF_PAIRS, r0, r1);                     \
        float u = tf_uniform(lo ? r0 : r1);                                     \
        if (u < freq) {                                                         \
            float4 XA = x4[jj * 3 + 0], XB = x4[jj * 3 + 1], XC = x4[jj * 3 + 2]; \
            float4 A = ar[k * 4 + 0], B = ar[k * 4 + 1];                        \
            float4 C = ar[k * 4 + 2], D = ar[k * 4 + 3];                        \
            float dot = DOT12(XA, XB, XC, A, B, C);                             \
            float d2 = fmaf(-2.0f, dot, xx_arr[jj]) + D.y;                      \
            float dist = sqrtf(fmaxf(fmaxf(d2, 0.0f), 1e-12f));                 \
            acc += (double)((q_arr[jj] * D.x) * (1.0f - dist));                 \
        }                                                                       \
    }

    for (int r = 0; r < 4; ++r) {
        const int jround = jblk + r * 256 + (w << 6);   // wave's 64-hit base
        const int j = jround + lane;
        unsigned long long m = (j < NHITS) ? mb64[(size_t)W * NHITS + j] : 0ull;
        unsigned int cnt = (unsigned)__popcll(m);

        unsigned int p = cnt;
#pragma unroll
        for (int off = 1; off < 64; off <<= 1) {
            unsigned int v = __shfl_up(p, off, 64);
            if (lane >= off) p += v;
        }
        const unsigned int excl = p - cnt;
        const unsigned int T = __shfl(p, 63, 64);

        // enqueue (capacity-guarded); residual bits stay in m
        {
            unsigned int pos = excl;
            unsigned short base = (unsigned short)(lane << 6);
            while (m && pos < QCAP) {
                int b = (int)__builtin_ctzll(m);
                m &= m - 1ull;
                qq[w][pos++] = (unsigned short)(base | (unsigned short)b);
            }
        }
        __syncthreads();

        const unsigned int Tc = (T < QCAP) ? T : QCAP;
        for (unsigned int i = lane; i < Tc; i += 64) {
            int desc = (int)qq[w][i];
            REP_PAIR(jround + (desc >> 6), (W << 6) + (desc & 63))
        }
        // overflow path (dormant): walk residual bits serially
        while (m) {
            int b = (int)__builtin_ctzll(m);
            m &= m - 1ull;
            REP_PAIR(j, (W << 6) + b)
        }
        __syncthreads();
    }
#undef REP_PAIR

    double rv = waveReduceD(acc);
    if (lane == 0) sd[w] = rv;
    __syncthreads();
    if (tid == 0) {
        double s = sd[0] + sd[1] + sd[2] + sd[3];
        if (s != 0.0) atomicAdd(acc_out, s);
    }
}

// fallback (ws too small for maskbuf): rescan + inline sampling. Host-selected.
__global__ __launch_bounds__(256)
void k_rep_fb(const float* __restrict__ x,
              const float* __restrict__ q_arr,
              const float* __restrict__ xx_arr,
              const int* __restrict__ oid,
              const float* __restrict__ arec,
              const unsigned int* __restrict__ nrep,
              double* __restrict__ acc_out) {
    __shared__ double sacc[4];
    const int tid = threadIdx.x;
    int t = blockIdx.x * 256 + tid;
    bool valid = t < HALF;
    int j0 = valid ? t : 0;
    int j1 = j0 + HALF;
    const float4* x4 = (const float4*)x;
    float4 X0a = x4[j0 * 3 + 0], X0b = x4[j0 * 3 + 1], X0c = x4[j0 * 3 + 2];
    float4 X1a = x4[j1 * 3 + 0], X1b = x4[j1 * 3 + 1], X1c = x4[j1 * 3 + 2];
    float xx0 = valid ? xx_arr[j0] : 3e9f;
    float xx1 = valid ? xx_arr[j1] : 3e9f;
    int o0 = oid[j0], o1 = oid[j1];
    const float4* ar = (const float4*)arec;
    const int kb = blockIdx.y * 128;
    const float freq = freq_from_n(*nrep);

    double acc = 0.0;
#define FB_G(G, J, XA, XB, XC, XX, OO, S1)                                      \
    {                                                                           \
        uint32_t m = 0, bit = 1u;                                               \
        int kbase = kb + (G) * 32;                                              \
        for (int kk = 0; kk < 32; ++kk, bit += bit) {                           \
            int k = kbase + kk;                                                 \
            float4 A = ar[k * 4 + 0];                                           \
            float4 B = ar[k * 4 + 1];                                           \
            float4 C = ar[k * 4 + 2];                                           \
            float a2 = ar[k * 4 + 3].y;                                         \
            float d0 = DOT12(XA, XB, XC, A, B, C);                              \
            float t0 = fmaf(-2.0f, d0, XX) + a2;                                \
            m |= (t0 < 1.0f && (OO) != k + 1) ? bit : 0u;                       \
        }                                                                       \
        while (m) {                                                             \
            int kk = __ffs(m) - 1; m &= m - 1;                                  \
            int k = kbase + kk;                                                 \
            uint32_t f = (uint32_t)(J) * NOBJ + (uint32_t)k;                    \
            uint32_t xa_ = (S1) ? (f - HALF_PAIRS) : f;                         \
            uint32_t b0_, b1_;                                                  \
            threefry2x32(0u, 42u, xa_, xa_ + HALF_PAIRS, b0_, b1_);             \
            float u = tf_uniform((S1) ? b1_ : b0_);                             \
            if (u < freq) {                                                     \
                float4 A = ar[k * 4 + 0], B = ar[k * 4 + 1], C = ar[k * 4 + 2], D = ar[k * 4 + 3]; \
                float dot = DOT12(XA, XB, XC, A, B, C);                         \
                float d2 = fmaf(-2.0f, dot, XX) + D.y;                          \
                float dist = sqrtf(fmaxf(fmaxf(d2, 0.0f), 1e-12f));             \
                acc += (double)((q_arr[J] * D.x) * (1.0f - dist));              \
            }                                                                   \
        }                                                                       \
    }
    FB_G(0, j0, X0a, X0b, X0c, xx0, o0, false)
    FB_G(1, j0, X0a, X0b, X0c, xx0, o0, false)
    FB_G(2, j0, X0a, X0b, X0c, xx0, o0, false)
    FB_G(3, j0, X0a, X0b, X0c, xx0, o0, false)
    FB_G(0, j1, X1a, X1b, X1c, xx1, o1, true)
    FB_G(1, j1, X1a, X1b, X1c, xx1, o1, true)
    FB_G(2, j1, X1a, X1b, X1c, xx1, o1, true)
    FB_G(3, j1, X1a, X1b, X1c, xx1, o1, true)
#undef FB_G

    double rv = waveReduceD(acc);
    if ((tid & 63) == 0) sacc[tid >> 6] = rv;
    __syncthreads();
    if (tid == 0) {
        double s = sacc[0] + sacc[1] + sacc[2] + sacc[3];
        if (s != 0.0) atomicAdd(acc_out, s);
    }
}

__global__ void k_final(const double* __restrict__ accs,
                        const unsigned long long* __restrict__ noise_cnt,
                        const unsigned int* __restrict__ nrep,
                        float* __restrict__ out) {
    float freq = freq_from_n(*nrep);
    double v_att = accs[0] / (double)NHITS;
    double v_rep = accs[1] / (double)freq / (double)NHITS;
    double l_cow = accs[2] / (double)NOBJ;
    unsigned long long nc = *noise_cnt;
    if (nc < 1ull) nc = 1ull;
    double l_noise = accs[3] / ((double)nc + 1e-9);
    double loss = v_att + v_rep + l_cow + 0.1 * l_noise;
    out[0] = (float)v_att;
    out[1] = (float)v_rep;
    out[2] = (float)l_cow;
    out[3] = (float)l_noise;
    out[4] = (float)loss;
}

// ---------------- launcher ----------------

extern "C" void kernel_launch(void* const* d_in, const int* in_sizes, int n_in,
                              void* d_out, int out_size, void* d_ws, size_t ws_size,
                              hipStream_t stream) {
    const float* beta = (const float*)d_in[0];
    const float* x    = (const float*)d_in[1];
    const int*   oid  = (const int*)d_in[2];
    float* out = (float*)d_out;

    char* ws = (char*)d_ws;
    double* v_att_sum = (double*)(ws + 0);
    double* v_rep_sum = (double*)(ws + 8);
    double* coward_sum = (double*)(ws + 16);
    double* noise_sum = (double*)(ws + 24);
    unsigned long long* noise_cnt = (unsigned long long*)(ws + 32);
    unsigned int* nrep = (unsigned int*)(ws + 40);
    unsigned long long* packed = (unsigned long long*)(ws + 64);
    float* arec = (float*)(ws + 8256);
    float* q_arr = (float*)(ws + 73792);
    float* xx_arr = (float*)(ws + 473792);
    unsigned long long* mb64 = (unsigned long long*)(ws + MASK_OFF);

    const int wsok = (ws_size >= WS_NEED) ? 1 : 0;

    // zero hdr (accumulators) + packed[1024] in one async memset (graph-capturable)
    hipMemsetAsync(d_ws, 0, 8256, stream);

    k_hits<<<(NHITS + 255) / 256, 256, 0, stream>>>(beta, x, oid, packed,
                                                    q_arr, xx_arr,
                                                    noise_sum, noise_cnt);
    k_alphas<<<4, 256, 0, stream>>>(packed, x, beta, q_arr, xx_arr,
                                    arec, coward_sum);

    // scan: blockIdx.x = hit chunk (256 of 25000 quarter-hits), y = 64-obj window
    dim3 gs((QUART + 255) / 256, 16);
    k_scan<<<gs, 256, 0, stream>>>(x, q_arr, xx_arr, oid, arec,
                                   mb64, nrep, v_att_sum, wsok);

    if (wsok) {
        dim3 gr((NHITS + 1023) / 1024, 16);
        k_rep<<<gr, 256, 0, stream>>>(x, q_arr, xx_arr, arec, mb64,
                                      nrep, v_rep_sum);
    } else {
        dim3 gfb((HALF + 255) / 256, 8);
        k_rep_fb<<<gfb, 256, 0, stream>>>(x, q_arr, xx_arr, oid, arec,
                                          nrep, v_rep_sum);
    }

    k_final<<<1, 1, 0, stream>>>((double*)ws, noise_cnt, nrep, out);
}

// Round 22
// 127.998 us; speedup vs baseline: 1.1099x; 1.1099x over previous
//
#include <hip/hip_runtime.h>
#include <stdint.h>

#define NHITS 100000
#define NOBJ  1024
#define HALF  50000
#define QUART 25000
#define HALF_PAIRS 51200000u   // NHITS*NOBJ/2
#define QCAP 2048              // per-wave queue entries (16 KB total LDS)

// ---------------- ws layout (bytes) ----------------
// 0:   double v_att_sum
// 8:   double v_rep_sum
// 16:  double coward_sum
// 24:  double noise_sum
// 32:  ull    noise_cnt
// 40:  u32    nrep
// 48:  float  freq (unused)
// 64:   ull   packed[1024]                        (64..8256)
// 8256: float arec[1024*16] {x[12], qa, xxa,0,0}  (8256..73792)
// 73792:  float q_arr[100000]                     (73792..473792)
// 473792: float xx_arr[100000]                    (473792..873792)
// 873792: u64 maskbuf[16][100000] = 12.8MB        (873792..13673792)

#define MASK_OFF 873792ull
#define WS_NEED (MASK_OFF + 16ull * NHITS * 8ull)

__device__ inline uint32_t rotl32(uint32_t x, int n) {
    return (x << n) | (x >> (32 - n));
}

__device__ inline void threefry2x32(uint32_t k0, uint32_t k1,
                                    uint32_t x0, uint32_t x1,
                                    uint32_t& o0, uint32_t& o1) {
    uint32_t ks2 = k0 ^ k1 ^ 0x1BD11BDAu;
    x0 += k0; x1 += k1;
#define TF_ROUND(r) { x0 += x1; x1 = rotl32(x1, r); x1 ^= x0; }
    TF_ROUND(13) TF_ROUND(15) TF_ROUND(26) TF_ROUND(6)
    x0 += k1;  x1 += ks2 + 1u;
    TF_ROUND(17) TF_ROUND(29) TF_ROUND(16) TF_ROUND(24)
    x0 += ks2; x1 += k0 + 2u;
    TF_ROUND(13) TF_ROUND(15) TF_ROUND(26) TF_ROUND(6)
    x0 += k0;  x1 += k1 + 3u;
    TF_ROUND(17) TF_ROUND(29) TF_ROUND(16) TF_ROUND(24)
    x0 += k1;  x1 += ks2 + 4u;
    TF_ROUND(13) TF_ROUND(15) TF_ROUND(26) TF_ROUND(6)
    x0 += ks2; x1 += k0 + 5u;
#undef TF_ROUND
    o0 = x0; o1 = x1;
}

__device__ inline float tf_uniform(uint32_t bits) {
    return __uint_as_float((bits >> 9) | 0x3f800000u) - 1.0f;
}

__device__ inline float freq_from_n(unsigned int n) {
    if (n < 1u) n = 1u;
    return fminf(100000.0f / (float)n, 1.0f);
}

__device__ inline double waveReduceD(double v) {
    for (int off = 32; off > 0; off >>= 1) v += __shfl_down(v, off, 64);
    return v;
}
__device__ inline unsigned int waveReduceU(unsigned int v) {
    for (int off = 32; off > 0; off >>= 1) v += __shfl_down(v, off, 64);
    return v;
}

#define DOT12(XA, XB, XC, A, B, C) \
    fmaf((XC).w, (C).w, fmaf((XC).z, (C).z, fmaf((XC).y, (C).y, fmaf((XC).x, (C).x, \
    fmaf((XB).w, (B).w, fmaf((XB).z, (B).z, fmaf((XB).y, (B).y, fmaf((XB).x, (B).x, \
    fmaf((XA).w, (A).w, fmaf((XA).z, (A).z, fmaf((XA).y, (A).y, (XA).x * (A).x)))))))))))

#define SS12(XA, XB, XC) DOT12(XA, XB, XC, XA, XB, XC)

// ---------------- kernels ----------------

__global__ void k_init(unsigned long long* packed, unsigned long long* hdr) {
    int t = blockIdx.x * blockDim.x + threadIdx.x;
    if (t < NOBJ) packed[t] = 0xFFFFFFFFull;
    if (t < 8)    hdr[t] = 0ull;
}

__global__ void k_hits(const float* __restrict__ beta,
                       const float* __restrict__ x,
                       const int* __restrict__ oid,
                       unsigned long long* __restrict__ packed,
                       float* __restrict__ q_arr,
                       float* __restrict__ xx_arr,
                       double* __restrict__ noise_sum,
                       unsigned long long* __restrict__ noise_cnt) {
    int j = blockIdx.x * blockDim.x + threadIdx.x;
    float nb = 0.0f;
    unsigned int nc = 0;
    if (j < NHITS) {
        float b = beta[j];
        int o = oid[j];
        float a = atanhf(b);
        float q = a * a + 0.1f;
        q_arr[j] = q;
        const float4* x4 = (const float4*)x;
        float4 A = x4[j * 3 + 0], B = x4[j * 3 + 1], C = x4[j * 3 + 2];
        xx_arr[j] = SS12(A, B, C);
        if (o > 0) {
            unsigned long long p =
                ((unsigned long long)__float_as_uint(q) << 32) |
                (unsigned long long)(0xFFFFFFFFu - (unsigned)j);
            atomicMax(&packed[o - 1], p);
        } else {
            nb = b; nc = 1;
        }
    }
    double rb = waveReduceD((double)nb);
    unsigned int rc = waveReduceU(nc);
    if ((threadIdx.x & 63) == 0) {
        if (rb != 0.0) atomicAdd(noise_sum, rb);
        if (rc)        atomicAdd(noise_cnt, (unsigned long long)rc);
    }
}

__global__ void k_alphas(const unsigned long long* __restrict__ packed,
                         const float* __restrict__ x,
                         const float* __restrict__ beta,
                         const float* __restrict__ q_arr,
                         const float* __restrict__ xx_arr,
                         float* __restrict__ arec,
                         double* __restrict__ coward_sum) {
    int k = blockIdx.x * blockDim.x + threadIdx.x;
    double c = 0.0;
    if (k < NOBJ) {
        unsigned idx = 0xFFFFFFFFu - (unsigned)(packed[k] & 0xFFFFFFFFull);
        const float4* x4 = (const float4*)x;
        float4 A = x4[idx * 3 + 0];
        float4 B = x4[idx * 3 + 1];
        float4 C = x4[idx * 3 + 2];
        float4 D;
        D.x = q_arr[idx]; D.y = xx_arr[idx]; D.z = 0.f; D.w = 0.f;
        float4* ar = (float4*)arec;
        ar[k * 4 + 0] = A;
        ar[k * 4 + 1] = B;
        ar[k * 4 + 2] = C;
        ar[k * 4 + 3] = D;
        c = 1.0 - (double)beta[idx];
    }
    double rc = waveReduceD(c);
    if ((threadIdx.x & 63) == 0) atomicAdd(coward_sum, rc);
}

// scan: round-13/14 champion body (named float4 hits + LDS object tile + scalar
// DOT12), 4 hits/thread, 64-obj window; fused v_att; u64 masks matching k_rep.
__global__ __launch_bounds__(256)
void k_scan(const float* __restrict__ x,
            const float* __restrict__ q_arr,
            const float* __restrict__ xx_arr,
            const int* __restrict__ oid,
            const float* __restrict__ arec,
            unsigned long long* __restrict__ mb64,
            unsigned int* __restrict__ nrep,
            double* __restrict__ v_att_sum,
            int do_write) {
    __shared__ float4 spack[64 * 4];    // 4 KB: 64 objects x {A,B,C,D}
    __shared__ unsigned int su[4];
    __shared__ double sd[4];
    const int tid = threadIdx.x;
    const int kb = blockIdx.y * 64;
    const float4* ar4 = (const float4*)arec;
    spack[tid] = ar4[kb * 4 + tid];
    __syncthreads();

    const int t = blockIdx.x * 256 + tid;
    const bool valid = t < QUART;
    const int j0 = valid ? t : 0;
    const int j1 = j0 + QUART;
    const int j2 = j0 + 2 * QUART;
    const int j3 = j0 + 3 * QUART;
    const float4* x4 = (const float4*)x;

    float4 X0a = x4[j0 * 3 + 0], X0b = x4[j0 * 3 + 1], X0c = x4[j0 * 3 + 2];
    float4 X1a = x4[j1 * 3 + 0], X1b = x4[j1 * 3 + 1], X1c = x4[j1 * 3 + 2];
    float4 X2a = x4[j2 * 3 + 0], X2b = x4[j2 * 3 + 1], X2c = x4[j2 * 3 + 2];
    float4 X3a = x4[j3 * 3 + 0], X3b = x4[j3 * 3 + 1], X3c = x4[j3 * 3 + 2];

    const float inval = valid ? 0.0f : 3e9f;
    const float xx0 = xx_arr[j0] + inval;
    const float xx1 = xx_arr[j1] + inval;
    const float xx2 = xx_arr[j2] + inval;
    const float xx3 = xx_arr[j3] + inval;
    const int o0 = valid ? oid[j0] : 0;
    const int o1 = valid ? oid[j1] : 0;
    const int o2 = valid ? oid[j2] : 0;
    const int o3 = valid ? oid[j3] : 0;

    uint32_t mA0 = 0, mA1 = 0, mB0 = 0, mB1 = 0;
    uint32_t mC0 = 0, mC1 = 0, mD0 = 0, mD1 = 0;

#define SCANH(BASE, MA, MB, MC, MD)                                         \
    {                                                                       \
        uint32_t bit = 1u;                                                  \
        for (int kk = 0; kk < 32; ++kk, bit += bit) {                       \
            int kl = (BASE) + kk;                                           \
            float4 A = spack[kl * 4 + 0];                                   \
            float4 B = spack[kl * 4 + 1];                                   \
            float4 C = spack[kl * 4 + 2];                                   \
            float a2 = spack[kl * 4 + 3].y;                                 \
            float d0 = DOT12(X0a, X0b, X0c, A, B, C);                       \
            float d1 = DOT12(X1a, X1b, X1c, A, B, C);                       \
            float d2 = DOT12(X2a, X2b, X2c, A, B, C);                       \
            float d3 = DOT12(X3a, X3b, X3c, A, B, C);                       \
            float t0 = fmaf(-2.0f, d0, xx0) + a2;                           \
            float t1 = fmaf(-2.0f, d1, xx1) + a2;                           \
            float t2 = fmaf(-2.0f, d2, xx2) + a2;                           \
            float t3 = fmaf(-2.0f, d3, xx3) + a2;                           \
            MA |= (t0 < 1.0f) ? bit : 0u;                                   \
            MB |= (t1 < 1.0f) ? bit : 0u;                                   \
            MC |= (t2 < 1.0f) ? bit : 0u;                                   \
            MD |= (t3 < 1.0f) ? bit : 0u;                                   \
        }                                                                   \
    }
    SCANH(0,  mA0, mB0, mC0, mD0)
    SCANH(32, mA1, mB1, mC1, mD1)
#undef SCANH

    // attractive: clear bit + fused v_att (same DOT12 order as the old k_att)
    double vatt = 0.0;
#define ATT_SLOT(O, J, XA, XB, XC, XXV, LO, HI)                             \
    if ((O) > 0) {                                                          \
        int rel = (O) - 1 - kb;                                             \
        if (rel >= 0 && rel < 64) {                                         \
            uint32_t bb = ~(1u << (rel & 31));                              \
            if (rel < 32) LO &= bb; else HI &= bb;                          \
            float4 A = spack[rel * 4 + 0];                                  \
            float4 B = spack[rel * 4 + 1];                                  \
            float4 C = spack[rel * 4 + 2];                                  \
            float4 D = spack[rel * 4 + 3];                                  \
            float dot = DOT12(XA, XB, XC, A, B, C);                         \
            float d2r = fmaf(-2.0f, dot, XXV) + D.y;                        \
            vatt += (double)((q_arr[J] * D.x) * fmaxf(d2r, 0.0f));          \
        }                                                                   \
    }
    ATT_SLOT(o0, j0, X0a, X0b, X0c, xx0, mA0, mA1)
    ATT_SLOT(o1, j1, X1a, X1b, X1c, xx1, mB0, mB1)
    ATT_SLOT(o2, j2, X2a, X2b, X2c, xx2, mC0, mC1)
    ATT_SLOT(o3, j3, X3a, X3b, X3c, xx3, mD0, mD1)
#undef ATT_SLOT

    const unsigned long long M0 = (unsigned long long)mA0 | ((unsigned long long)mA1 << 32);
    const unsigned long long M1 = (unsigned long long)mB0 | ((unsigned long long)mB1 << 32);
    const unsigned long long M2 = (unsigned long long)mC0 | ((unsigned long long)mC1 << 32);
    const unsigned long long M3 = (unsigned long long)mD0 | ((unsigned long long)mD1 << 32);

    if (do_write && valid) {
        const size_t W = (size_t)blockIdx.y;
        mb64[W * NHITS + j0] = M0;
        mb64[W * NHITS + j1] = M1;
        mb64[W * NHITS + j2] = M2;
        mb64[W * NHITS + j3] = M3;
    }

    unsigned int cnt = (unsigned)(__popcll(M0) + __popcll(M1) +
                                  __popcll(M2) + __popcll(M3));
    unsigned int rc = waveReduceU(cnt);
    double rv = waveReduceD(vatt);
    if ((tid & 63) == 0) { su[tid >> 6] = rc; sd[tid >> 6] = rv; }
    __syncthreads();
    if (tid == 0) {
        unsigned int s = su[0] + su[1] + su[2] + su[3];
        if (s) atomicAdd(nrep, s);
        double v = sd[0] + sd[1] + sd[2] + sd[3];
        if (v != 0.0) atomicAdd(v_att_sum, v);
    }
}

// rep: u64 mask words, 4 rounds/block, per-wave LDS queue balancing.
// grid (98, 16): blockIdx.y = u64 word index W (objects [W*64, W*64+64)).
// QCAP=2048 entries/wave (16 KB LDS) with dormant overflow guard.
__global__ __launch_bounds__(256)
void k_rep(const float* __restrict__ x,
           const float* __restrict__ q_arr,
           const float* __restrict__ xx_arr,
           const float* __restrict__ arec,
           const unsigned long long* __restrict__ mb64,
           const unsigned int* __restrict__ nrep,
           double* __restrict__ acc_out) {
    __shared__ unsigned short qq[4][QCAP];   // 16 KB
    __shared__ double sd[4];
    const int tid = threadIdx.x;
    const int lane = tid & 63;
    const int w = tid >> 6;
    const int W = blockIdx.y;
    const int jblk = blockIdx.x * 1024;
    const float freq = freq_from_n(*nrep);
    const float4* x4 = (const float4*)x;
    const float4* ar = (const float4*)arec;
    double acc = 0.0;

#define REP_PAIR(JJ, KK)                                                        \
    {                                                                           \
        int jj = (JJ); int k = (KK);                                            \
        uint32_t f = (uint32_t)jj * NOBJ + (uint32_t)k;                         \
        bool lo = jj < HALF;                                                    \
        uint32_t xa = lo ? f : (f - HALF_PAIRS);                                \
        uint32_t r0, r1;                                                        \
        threefry2x32(0u, 42u, xa, xa + HALF_PAIRS, r0, r1);                     \
        float u = tf_uniform(lo ? r0 : r1);                                     \
        if (u < freq) {                                                         \
            float4 XA = x4[jj * 3 + 0], XB = x4[jj * 3 + 1], XC = x4[jj * 3 + 2]; \
            float4 A = ar[k * 4 + 0], B = ar[k * 4 + 1];                        \
            float4 C = ar[k * 4 + 2], D = ar[k * 4 + 3];                        \
            float dot = DOT12(XA, XB, XC, A, B, C);                             \
            float d2 = fmaf(-2.0f, dot, xx_arr[jj]) + D.y;                      \
            float dist = sqrtf(fmaxf(fmaxf(d2, 0.0f), 1e-12f));                 \
            acc += (double)((q_arr[jj] * D.x) * (1.0f - dist));                 \
        }                                                                       \
    }

    for (int r = 0; r < 4; ++r) {
        const int jround = jblk + r * 256 + (w << 6);   // wave's 64-hit base
        const int j = jround + lane;
        unsigned long long m = (j < NHITS) ? mb64[(size_t)W * NHITS + j] : 0ull;
        unsigned int cnt = (unsigned)__popcll(m);

        unsigned int p = cnt;
#pragma unroll
        for (int off = 1; off < 64; off <<= 1) {
            unsigned int v = __shfl_up(p, off, 64);
            if (lane >= off) p += v;
        }
        const unsigned int excl = p - cnt;
        const unsigned int T = __shfl(p, 63, 64);

        // enqueue (capacity-guarded); residual bits stay in m
        {
            unsigned int pos = excl;
            unsigned short base = (unsigned short)(lane << 6);
            while (m && pos < QCAP) {
                int b = (int)__builtin_ctzll(m);
                m &= m - 1ull;
                qq[w][pos++] = (unsigned short)(base | (unsigned short)b);
            }
        }
        __syncthreads();

        const unsigned int Tc = (T < QCAP) ? T : QCAP;
        for (unsigned int i = lane; i < Tc; i += 64) {
            int desc = (int)qq[w][i];
            REP_PAIR(jround + (desc >> 6), (W << 6) + (desc & 63))
        }
        // overflow path (dormant): walk residual bits serially
        while (m) {
            int b = (int)__builtin_ctzll(m);
            m &= m - 1ull;
            REP_PAIR(j, (W << 6) + b)
        }
        __syncthreads();
    }
#undef REP_PAIR

    double rv = waveReduceD(acc);
    if (lane == 0) sd[w] = rv;
    __syncthreads();
    if (tid == 0) {
        double s = sd[0] + sd[1] + sd[2] + sd[3];
        if (s != 0.0) atomicAdd(acc_out, s);
    }
}

// fallback (ws too small for maskbuf): rescan + inline sampling. Host-selected.
__global__ __launch_bounds__(256)
void k_rep_fb(const float* __restrict__ x,
              const float* __restrict__ q_arr,
              const float* __restrict__ xx_arr,
              const int* __restrict__ oid,
              const float* __restrict__ arec,
              const unsigned int* __restrict__ nrep,
              double* __restrict__ acc_out) {
    __shared__ double sacc[4];
    const int tid = threadIdx.x;
    int t = blockIdx.x * 256 + tid;
    bool valid = t < HALF;
    int j0 = valid ? t : 0;
    int j1 = j0 + HALF;
    const float4* x4 = (const float4*)x;
    float4 X0a = x4[j0 * 3 + 0], X0b = x4[j0 * 3 + 1], X0c = x4[j0 * 3 + 2];
    float4 X1a = x4[j1 * 3 + 0], X1b = x4[j1 * 3 + 1], X1c = x4[j1 * 3 + 2];
    float xx0 = valid ? xx_arr[j0] : 3e9f;
    float xx1 = valid ? xx_arr[j1] : 3e9f;
    int o0 = oid[j0], o1 = oid[j1];
    const float4* ar = (const float4*)arec;
    const int kb = blockIdx.y * 128;
    const float freq = freq_from_n(*nrep);

    double acc = 0.0;
#define FB_G(G, J, XA, XB, XC, XX, OO, S1)                                      \
    {                                                                           \
        uint32_t m = 0, bit = 1u;                                               \
        int kbase = kb + (G) * 32;                                              \
        for (int kk = 0; kk < 32; ++kk, bit += bit) {                           \
            int k = kbase + kk;                                                 \
            float4 A = ar[k * 4 + 0];                                           \
            float4 B = ar[k * 4 + 1];                                           \
            float4 C = ar[k * 4 + 2];                                           \
            float a2 = ar[k * 4 + 3].y;                                         \
            float d0 = DOT12(XA, XB, XC, A, B, C);                              \
            float t0 = fmaf(-2.0f, d0, XX) + a2;                                \
            m |= (t0 < 1.0f && (OO) != k + 1) ? bit : 0u;                       \
        }                                                                       \
        while (m) {                                                             \
            int kk = __ffs(m) - 1; m &= m - 1;                                  \
            int k = kbase + kk;                                                 \
            uint32_t f = (uint32_t)(J) * NOBJ + (uint32_t)k;                    \
            uint32_t xa_ = (S1) ? (f - HALF_PAIRS) : f;                         \
            uint32_t b0_, b1_;                                                  \
            threefry2x32(0u, 42u, xa_, xa_ + HALF_PAIRS, b0_, b1_);             \
            float u = tf_uniform((S1) ? b1_ : b0_);                             \
            if (u < freq) {                                                     \
                float4 A = ar[k * 4 + 0], B = ar[k * 4 + 1], C = ar[k * 4 + 2], D = ar[k * 4 + 3]; \
                float dot = DOT12(XA, XB, XC, A, B, C);                         \
                float d2 = fmaf(-2.0f, dot, XX) + D.y;                          \
                float dist = sqrtf(fmaxf(fmaxf(d2, 0.0f), 1e-12f));             \
                acc += (double)((q_arr[J] * D.x) * (1.0f - dist));              \
            }                                                                   \
        }                                                                       \
    }
    FB_G(0, j0, X0a, X0b, X0c, xx0, o0, false)
    FB_G(1, j0, X0a, X0b, X0c, xx0, o0, false)
    FB_G(2, j0, X0a, X0b, X0c, xx0, o0, false)
    FB_G(3, j0, X0a, X0b, X0c, xx0, o0, false)
    FB_G(0, j1, X1a, X1b, X1c, xx1, o1, true)
    FB_G(1, j1, X1a, X1b, X1c, xx1, o1, true)
    FB_G(2, j1, X1a, X1b, X1c, xx1, o1, true)
    FB_G(3, j1, X1a, X1b, X1c, xx1, o1, true)
#undef FB_G

    double rv = waveReduceD(acc);
    if ((tid & 63) == 0) sacc[tid >> 6] = rv;
    __syncthreads();
    if (tid == 0) {
        double s = sacc[0] + sacc[1] + sacc[2] + sacc[3];
        if (s != 0.0) atomicAdd(acc_out, s);
    }
}

__global__ void k_final(const double* __restrict__ accs,
                        const unsigned long long* __restrict__ noise_cnt,
                        const unsigned int* __restrict__ nrep,
                        float* __restrict__ out) {
    float freq = freq_from_n(*nrep);
    double v_att = accs[0] / (double)NHITS;
    double v_rep = accs[1] / (double)freq / (double)NHITS;
    double l_cow = accs[2] / (double)NOBJ;
    unsigned long long nc = *noise_cnt;
    if (nc < 1ull) nc = 1ull;
    double l_noise = accs[3] / ((double)nc + 1e-9);
    double loss = v_att + v_rep + l_cow + 0.1 * l_noise;
    out[0] = (float)v_att;
    out[1] = (float)v_rep;
    out[2] = (float)l_cow;
    out[3] = (float)l_noise;
    out[4] = (float)loss;
}

// ---------------- launcher ----------------

extern "C" void kernel_launch(void* const* d_in, const int* in_sizes, int n_in,
                              void* d_out, int out_size, void* d_ws, size_t ws_size,
                              hipStream_t stream) {
    const float* beta = (const float*)d_in[0];
    const float* x    = (const float*)d_in[1];
    const int*   oid  = (const int*)d_in[2];
    float* out = (float*)d_out;

    char* ws = (char*)d_ws;
    double* v_att_sum = (double*)(ws + 0);
    double* v_rep_sum = (double*)(ws + 8);
    double* coward_sum = (double*)(ws + 16);
    double* noise_sum = (double*)(ws + 24);
    unsigned long long* noise_cnt = (unsigned long long*)(ws + 32);
    unsigned int* nrep = (unsigned int*)(ws + 40);
    unsigned long long* packed = (unsigned long long*)(ws + 64);
    float* arec = (float*)(ws + 8256);
    float* q_arr = (float*)(ws + 73792);
    float* xx_arr = (float*)(ws + 473792);
    unsigned long long* mb64 = (unsigned long long*)(ws + MASK_OFF);

    const int wsok = (ws_size >= WS_NEED) ? 1 : 0;

    k_init<<<4, 256, 0, stream>>>(packed, (unsigned long long*)ws);
    k_hits<<<(NHITS + 255) / 256, 256, 0, stream>>>(beta, x, oid, packed,
                                                    q_arr, xx_arr,
                                                    noise_sum, noise_cnt);
    k_alphas<<<4, 256, 0, stream>>>(packed, x, beta, q_arr, xx_arr,
                                    arec, coward_sum);

    // scan: blockIdx.x = hit chunk (256 of 25000 quarter-hits), y = 64-obj window
    dim3 gs((QUART + 255) / 256, 16);
    k_scan<<<gs, 256, 0, stream>>>(x, q_arr, xx_arr, oid, arec,
                                   mb64, nrep, v_att_sum, wsok);

    if (wsok) {
        dim3 gr((NHITS + 1023) / 1024, 16);
        k_rep<<<gr, 256, 0, stream>>>(x, q_arr, xx_arr, arec, mb64,
                                      nrep, v_rep_sum);
    } else {
        dim3 gfb((HALF + 255) / 256, 8);
        k_rep_fb<<<gfb, 256, 0, stream>>>(x, q_arr, xx_arr, oid, arec,
                                          nrep, v_rep_sum);
    }

    k_final<<<1, 1, 0, stream>>>((double*)ws, noise_cnt, nrep, out);
}